// Round 1
// 258.299 us; speedup vs baseline: 1.3180x; 1.3180x over previous
//
#include <hip/hip_runtime.h>
#include <hip/hip_bf16.h>
#include <math.h>

#define B 4
#define A 256
#define NN 64
#define NCB 128
#define NF 128
#define NSB 50
#define BA (B*A)
#define PAIRS (BA*NN)

typedef __bf16 bf;
typedef __attribute__((ext_vector_type(8))) __bf16 bfrag8;
typedef __attribute__((ext_vector_type(4))) float ffrag4;

// ---- module-scope scratch (never touches inputs / d_ws) ----
__device__ __attribute__((aligned(16))) bf    g_yib[BA*NF];          // bf16(xi @ in2f_W)
__device__ __attribute__((aligned(16))) bf    g_vij[(size_t)PAIRS*NCB]; // bf16 vij stash (16 MB)
__device__ __attribute__((aligned(16))) float g_vik[BA*NCB*3];       // fp32 Vik rows [ba][c*3+d]
// transposed bf16 weights, layout [n][k] (k contiguous)
__device__ __attribute__((aligned(16))) bf g_tf1[NF*64];
__device__ __attribute__((aligned(16))) bf g_tf2[NF*NF];
__device__ __attribute__((aligned(16))) bf g_tfo[NF*NF];
__device__ __attribute__((aligned(16))) bf g_tp1[NF*NF];
__device__ __attribute__((aligned(16))) bf g_tp2[NF*NF];
__device__ __attribute__((aligned(16))) bf g_te1[NF*NF];
__device__ __attribute__((aligned(16))) bf g_te2[NF*NF];

// fast ssp: softplus(x)-ln2 via hw v_exp_f32/v_log_f32 (libm expf/log1pf was
// the dominant VALU cost: ~70 inst/call vs ~7 here; err ~1e-7 << bf16 rounding)
__device__ __forceinline__ float ssp(float x){
    float e = __expf(-fabsf(x));
    return fmaxf(x, 0.f) + __logf(1.f + e) - 0.6931471805599453f;
}

// ---- weight pre-transpose: W[k][n] fp32 -> Wt[n][k] bf16 (pad k for filter W1) ----
// 8-way split per matrix (56 blocks) so we don't leave 249 CUs idle.
__global__ __launch_bounds__(256)
void k_wt(const float* __restrict__ f1, const float* __restrict__ f2,
          const float* __restrict__ fo, const float* __restrict__ p1,
          const float* __restrict__ p2, const float* __restrict__ e1,
          const float* __restrict__ e2){
    int s = blockIdx.x >> 3, part = blockIdx.x & 7;
    const float* src; bf* dst; int kb, realK;
    if (s == 0){ src = f1; dst = g_tf1; kb = 6; realK = NSB; }
    else {
        kb = 7; realK = 128;
        src = (s==1)?f2:(s==2)?fo:(s==3)?p1:(s==4)?p2:(s==5)?e1:e2;
        dst = (s==1)?g_tf2:(s==2)?g_tfo:(s==3)?g_tp1:(s==4)?g_tp2:(s==5)?g_te1:g_te2;
    }
    int total = NF << kb;
    int chunk = total >> 3;
    int end = (part + 1) * chunk;
    for (int e = part*chunk + threadIdx.x; e < end; e += 256){
        int n = e >> kb, k = e & ((1<<kb)-1);
        dst[e] = (k < realK) ? (bf)src[k*NF + n] : (bf)0.f;
    }
}

// ---- g_yib[row][f] = bf16( xi[row,:] @ in2f_W[:,f] ) ----
__global__ __launch_bounds__(NF)
void k_yi(const float* __restrict__ xi, const float* __restrict__ W){
    int row = blockIdx.x, f = threadIdx.x;
    __shared__ float x[NCB];
    x[f] = xi[row*NCB + f];
    __syncthreads();
    float s = 0.f;
    #pragma unroll 16
    for (int c = 0; c < NCB; c++) s += x[c]*W[c*NF + f];
    g_yib[row*NF + f] = (bf)s;
}

// ---- LDS staging helpers ----
__device__ __forceinline__ void stage_w128(bf* __restrict__ sW, const bf* __restrict__ g,
                                           int half, int tid){
    // 64 n-rows x 128 k, LDS stride 136
    #pragma unroll
    for (int i = 0; i < 4; i++){
        int r  = i*16 + (tid >> 4);
        int cp = (tid & 15)*8;
        *(bfrag8*)&sW[r*136 + cp] = *(const bfrag8*)&g[(half*64 + r)*128 + cp];
    }
}
__device__ __forceinline__ void stage_w64(bf* __restrict__ sW, const bf* __restrict__ g,
                                          int half, int tid){
    // 64 n-rows x 64 k, LDS stride 72
    #pragma unroll
    for (int i = 0; i < 2; i++){
        int r  = i*32 + (tid >> 3);
        int cp = (tid & 7)*8;
        *(bfrag8*)&sW[r*72 + cp] = *(const bfrag8*)&g[(half*64 + r)*64 + cp];
    }
}
__device__ __forceinline__ void gemm4(const bf* __restrict__ sW, const bfrag8 afr[4],
                                      ffrag4 acc[4], int q, int c16){
    #pragma unroll
    for (int nt = 0; nt < 4; nt++){
        ffrag4 a = {0.f,0.f,0.f,0.f};
        #pragma unroll
        for (int kt = 0; kt < 4; kt++){
            bfrag8 bv = *(const bfrag8*)&sW[(nt*16 + c16)*136 + kt*32 + q*8];
            a = __builtin_amdgcn_mfma_f32_16x16x32_bf16(afr[kt], bv, a, 0, 0, 0);
        }
        acc[nt] = a;
    }
}
__device__ __forceinline__ void gemm2(const bf* __restrict__ sW, const bfrag8 afr[2],
                                      ffrag4 acc[4], int q, int c16){
    #pragma unroll
    for (int nt = 0; nt < 4; nt++){
        ffrag4 a = {0.f,0.f,0.f,0.f};
        #pragma unroll
        for (int kt = 0; kt < 2; kt++){
            bfrag8 bv = *(const bfrag8*)&sW[(nt*16 + c16)*72 + kt*32 + q*8];
            a = __builtin_amdgcn_mfma_f32_16x16x32_bf16(afr[kt], bv, a, 0, 0, 0);
        }
        acc[nt] = a;
    }
}

__global__ __launch_bounds__(256, 3)
void k_main(const float* __restrict__ r_ij, const float* __restrict__ cos_ij,
            const float* __restrict__ f_ij, const float* __restrict__ mask,
            const int* __restrict__ neighbors,
            const float* __restrict__ fb1, const float* __restrict__ fb2,
            const float* __restrict__ f2b,
            const float* __restrict__ aW1, const float* __restrict__ ab1,
            const float* __restrict__ aW2, const float* __restrict__ ab2,
            const float* __restrict__ pb1, const float* __restrict__ pb2,
            const float* __restrict__ eb1, const float* __restrict__ eb2,
            float* __restrict__ out_vi){
    const int tid  = threadIdx.x;
    const int ba   = blockIdx.x;          // atom (b*A + a)
    const int b    = ba >> 8;
    const int w    = tid >> 6;            // wave 0..3 -> m-tile (rows w*16..w*16+15)
    const int lane = tid & 63;
    const int q    = lane >> 4;
    const int c16  = lane & 15;
    const int arow = w*16 + c16;          // A-frag row for this lane

    // sW blob also hosts the finale scratch (sVs/sVk/sVsum/sHa) AFTER the last
    // sW read + a barrier — saves 9.2 KB LDS -> 53,760 B total -> 3 blocks/CU.
    __shared__ __attribute__((aligned(16))) char sWb[64*136*2];
    bf* const sW = (bf*)sWb;
    __shared__ __attribute__((aligned(16))) bf sA [64*136];   // h1/u/v
    __shared__ __attribute__((aligned(16))) bf sA2[64*136];   // f / hp / vij / he
    __shared__ float sCosM[64*4];   // cos0,cos1,cos2,mask
    __shared__ float sCr[64];
    __shared__ int   sJb[64];       // (b*A+j)*NF

    // ---- preload: f -> sA2 (K padded to 64), per-pair scalars ----
    #pragma unroll
    for (int i = 0; i < 16; i++){
        int e = tid + i*256;                       // 64*64
        int row = e >> 6, col = e & 63;
        float v = (col < NSB) ? f_ij[(ba*64 + row)*NSB + col] : 0.f;
        sA2[row*136 + col] = (bf)v;
    }
    if (tid < 64){
        int p = ba*64 + tid;
        sCosM[tid*4+0] = cos_ij[p*3+0];
        sCosM[tid*4+1] = cos_ij[p*3+1];
        sCosM[tid*4+2] = cos_ij[p*3+2];
        sCosM[tid*4+3] = mask[p];
        float r = r_ij[p];
        sCr[tid] = (r < 5.f) ? 0.5f*(__cosf(r*0.62831853071795864769f) + 1.f) : 0.f;
        int j = neighbors[p] & (A-1);
        sJb[tid] = (b*A + j)*NF;
    }
    __syncthreads();

    bfrag8 afr4[4]; bfrag8 afr2[2]; ffrag4 acc[4];

    // ================= S1: h1 = ssp(f @ fW1 + fb1) -> sA =================
    #pragma unroll
    for (int kt = 0; kt < 2; kt++) afr2[kt] = *(const bfrag8*)&sA2[arow*136 + kt*32 + q*8];
    #pragma unroll
    for (int half = 0; half < 2; half++){
        if (half) __syncthreads();
        stage_w64(sW, g_tf1, half, tid);
        __syncthreads();
        gemm2(sW, afr2, acc, q, c16);
        #pragma unroll
        for (int nt = 0; nt < 4; nt++){
            int col = (half*4 + nt)*16 + c16;
            float bias = fb1[col];
            #pragma unroll
            for (int rg = 0; rg < 4; rg++){
                int row = w*16 + q*4 + rg;
                sA[row*136 + col] = (bf)ssp(acc[nt][rg] + bias);
            }
        }
    }
    __syncthreads();

    // ===== S2: Wf = (h1 @ fW2 + fb2)*C ; u = yj*Wf -> sA (in-place) =====
    #pragma unroll
    for (int kt = 0; kt < 4; kt++) afr4[kt] = *(const bfrag8*)&sA[arow*136 + kt*32 + q*8];
    #pragma unroll
    for (int half = 0; half < 2; half++){
        if (half) __syncthreads();
        stage_w128(sW, g_tf2, half, tid);
        __syncthreads();
        gemm4(sW, afr4, acc, q, c16);
        #pragma unroll
        for (int nt = 0; nt < 4; nt++){
            int col = (half*4 + nt)*16 + c16;
            float bias = fb2[col];
            #pragma unroll
            for (int rg = 0; rg < 4; rg++){
                int row = w*16 + q*4 + rg;
                float wf = (acc[nt][rg] + bias) * sCr[row];
                float u  = (float)g_yib[sJb[row] + col] * wf;
                sA[row*136 + col] = (bf)u;
            }
        }
    }
    __syncthreads();

    // ===== S3: v = ssp(u @ f2W + f2b) -> sA (in-place); vsum in registers =====
    float vsAll[8];
    #pragma unroll
    for (int t = 0; t < 8; t++) vsAll[t] = 0.f;
    #pragma unroll
    for (int kt = 0; kt < 4; kt++) afr4[kt] = *(const bfrag8*)&sA[arow*136 + kt*32 + q*8];
    #pragma unroll
    for (int half = 0; half < 2; half++){
        if (half) __syncthreads();
        stage_w128(sW, g_tfo, half, tid);
        __syncthreads();
        gemm4(sW, afr4, acc, q, c16);
        #pragma unroll
        for (int nt = 0; nt < 4; nt++){
            int col = (half*4 + nt)*16 + c16;
            float bias = f2b[col];
            #pragma unroll
            for (int rg = 0; rg < 4; rg++){
                int row = w*16 + q*4 + rg;
                float v = ssp(acc[nt][rg] + bias);
                sA[row*136 + col] = (bf)v;
                vsAll[half*4 + nt] += v * sCosM[row*4+3];
            }
        }
    }
    __syncthreads();

    // ================= S4: hp = ssp(v @ pW1 + pb1) -> sA2 =================
    #pragma unroll
    for (int kt = 0; kt < 4; kt++) afr4[kt] = *(const bfrag8*)&sA[arow*136 + kt*32 + q*8];
    #pragma unroll
    for (int half = 0; half < 2; half++){
        if (half) __syncthreads();
        stage_w128(sW, g_tp1, half, tid);
        __syncthreads();
        gemm4(sW, afr4, acc, q, c16);
        #pragma unroll
        for (int nt = 0; nt < 4; nt++){
            int col = (half*4 + nt)*16 + c16;
            float bias = pb1[col];
            #pragma unroll
            for (int rg = 0; rg < 4; rg++){
                int row = w*16 + q*4 + rg;
                sA2[row*136 + col] = (bf)ssp(acc[nt][rg] + bias);
            }
        }
    }
    __syncthreads();

    // ============ S5: vij = hp @ pW2 + pb2 -> sA2 (in-place, bf16) ============
    #pragma unroll
    for (int kt = 0; kt < 4; kt++) afr4[kt] = *(const bfrag8*)&sA2[arow*136 + kt*32 + q*8];
    #pragma unroll
    for (int half = 0; half < 2; half++){
        if (half) __syncthreads();
        stage_w128(sW, g_tp2, half, tid);
        __syncthreads();
        gemm4(sW, afr4, acc, q, c16);
        #pragma unroll
        for (int nt = 0; nt < 4; nt++){
            int col = (half*4 + nt)*16 + c16;
            float bias = pb2[col];
            #pragma unroll
            for (int rg = 0; rg < 4; rg++){
                int row = w*16 + q*4 + rg;
                sA2[row*136 + col] = (bf)(acc[nt][rg] + bias);
            }
        }
    }
    __syncthreads();

    // ===== S6: copy vij -> g_vij; he = ssp(v @ eW1 + eb1) -> sA2 =====
    #pragma unroll
    for (int i = 0; i < 4; i++){
        int row = i*16 + (tid >> 4);
        int cp  = (tid & 15)*8;
        *(bfrag8*)&g_vij[((size_t)ba*64 + row)*128 + cp] = *(const bfrag8*)&sA2[row*136 + cp];
    }
    #pragma unroll
    for (int kt = 0; kt < 4; kt++) afr4[kt] = *(const bfrag8*)&sA[arow*136 + kt*32 + q*8];
    #pragma unroll
    for (int half = 0; half < 2; half++){
        if (half) __syncthreads();
        stage_w128(sW, g_te1, half, tid);
        __syncthreads();
        gemm4(sW, afr4, acc, q, c16);
        #pragma unroll
        for (int nt = 0; nt < 4; nt++){
            int col = (half*4 + nt)*16 + c16;
            float bias = eb1[col];
            #pragma unroll
            for (int rg = 0; rg < 4; rg++){
                int row = w*16 + q*4 + rg;
                sA2[row*136 + col] = (bf)ssp(acc[nt][rg] + bias);
            }
        }
    }
    __syncthreads();

    // ===== S7: vik = he @ eW2 + eb2 ; Vik partials (registers only) =====
    float vkAll[8][3];
    #pragma unroll
    for (int t = 0; t < 8; t++){ vkAll[t][0]=0.f; vkAll[t][1]=0.f; vkAll[t][2]=0.f; }
    #pragma unroll
    for (int kt = 0; kt < 4; kt++) afr4[kt] = *(const bfrag8*)&sA2[arow*136 + kt*32 + q*8];
    #pragma unroll
    for (int half = 0; half < 2; half++){
        if (half) __syncthreads();
        stage_w128(sW, g_te2, half, tid);
        __syncthreads();
        gemm4(sW, afr4, acc, q, c16);
        #pragma unroll
        for (int nt = 0; nt < 4; nt++){
            float bias = eb2[(half*4 + nt)*16 + c16];
            #pragma unroll
            for (int rg = 0; rg < 4; rg++){
                int row = w*16 + q*4 + rg;
                float vik = (acc[nt][rg] + bias) * sCosM[row*4+3];
                vkAll[half*4 + nt][0] += vik * sCosM[row*4+0];
                vkAll[half*4 + nt][1] += vik * sCosM[row*4+1];
                vkAll[half*4 + nt][2] += vik * sCosM[row*4+2];
            }
        }
    }

    // ===== finale: all sW reads done -> barrier, then reuse blob as scratch =====
    __syncthreads();
    float* const sVs   = (float*)sWb;            // 4*128 floats  (bytes    0..2047)
    float* const sVk   = (float*)(sWb + 2048);   // 4*384 floats  (bytes 2048..8191)
    float* const sVsum = (float*)(sWb + 8192);   // 128 floats    (bytes 8192..8703)
    float* const sHa   = (float*)(sWb + 8704);   // 128 floats    (bytes 8704..9215)
    #pragma unroll
    for (int t = 0; t < 8; t++){
        float v = vsAll[t];
        v += __shfl_xor(v, 16);
        v += __shfl_xor(v, 32);
        if (q == 0) sVs[w*128 + t*16 + c16] = v;
    }
    #pragma unroll
    for (int t = 0; t < 8; t++){
        #pragma unroll
        for (int d = 0; d < 3; d++){
            float v = vkAll[t][d];
            v += __shfl_xor(v, 16);
            v += __shfl_xor(v, 32);
            if (q == 0) sVk[w*384 + (t*16 + c16)*3 + d] = v;
        }
    }
    __syncthreads();

    for (int e = tid; e < 384; e += 256)
        g_vik[ba*384 + e] = sVk[e] + sVk[384+e] + sVk[768+e] + sVk[1152+e];
    if (tid < 128)
        sVsum[tid] = sVs[tid] + sVs[128+tid] + sVs[256+tid] + sVs[384+tid];
    __syncthreads();
    if (tid < 128){
        float acc2 = ab1[tid];
        #pragma unroll 16
        for (int k = 0; k < 128; k++) acc2 += sVsum[k]*aW1[k*128 + tid];
        sHa[tid] = ssp(acc2);
    }
    __syncthreads();
    if (tid < 128){
        float acc2 = ab2[tid];
        #pragma unroll 16
        for (int k = 0; k < 128; k++) acc2 += sHa[k]*aW2[k*128 + tid];
        out_vi[ba*128 + tid] = acc2;
    }
}

// ---- V[p,c,d] = vij[p,c]*cos[p,d] + Vik[ba] + Vik[j-row] ----
// One block per atom (1024 blocks x 256 thr): Vik[ba]/cos/j staged once in LDS,
// 64 pairs looped with NO per-pair barrier; nontemporal streaming stores.
__global__ __launch_bounds__(256)
void k_V(const float* __restrict__ cos_ij, const int* __restrict__ nbrs,
         float* __restrict__ outV){
    const int ba  = blockIdx.x;
    const int b   = ba >> 8;
    const int tid = threadIdx.x;
    const int g   = tid >> 7;        // pair sub-group 0/1
    const int t   = tid & 127;       // channel c
    __shared__ float sVa[384];
    __shared__ float sC[64*3];
    __shared__ int   sJ[64];
    for (int e = tid; e < 384; e += 256) sVa[e] = g_vik[ba*384 + e];
    if (tid < 64){
        int p = ba*64 + tid;
        sJ[tid] = (b*A + (nbrs[p] & (A-1)))*384;
        sC[tid*3+0] = cos_ij[p*3+0];
        sC[tid*3+1] = cos_ij[p*3+1];
        sC[tid*3+2] = cos_ij[p*3+2];
    }
    __syncthreads();
    const int t3 = t*3;
    const float a0 = sVa[t3+0], a1 = sVa[t3+1], a2 = sVa[t3+2];
    #pragma unroll 2
    for (int i = 0; i < 32; i++){
        int n = i*2 + g;
        size_t p = (size_t)ba*64 + n;
        float vv = (float)g_vij[p*128 + t];
        const float* vjp = g_vik + sJ[n] + t3;
        float c0 = sC[n*3+0], c1 = sC[n*3+1], c2 = sC[n*3+2];
        float* o = outV + p*384 + t3;
        __builtin_nontemporal_store(fmaf(vv, c0, a0 + vjp[0]), o+0);
        __builtin_nontemporal_store(fmaf(vv, c1, a1 + vjp[1]), o+1);
        __builtin_nontemporal_store(fmaf(vv, c2, a2 + vjp[2]), o+2);
    }
}

extern "C" void kernel_launch(void* const* d_in, const int* in_sizes, int n_in,
                              void* d_out, int out_size, void* d_ws, size_t ws_size,
                              hipStream_t stream){
    const float* xi      = (const float*)d_in[0];
    const float* r_ij    = (const float*)d_in[1];
    const float* cos_ij  = (const float*)d_in[2];
    const float* f_ij    = (const float*)d_in[3];
    const float* nmask   = (const float*)d_in[4];
    const float* fW1     = (const float*)d_in[5];
    const float* fb1     = (const float*)d_in[6];
    const float* fW2     = (const float*)d_in[7];
    const float* fb2     = (const float*)d_in[8];
    const float* in2f_W  = (const float*)d_in[9];
    const float* f2W     = (const float*)d_in[10];
    const float* f2b     = (const float*)d_in[11];
    const float* aW1     = (const float*)d_in[12];
    const float* ab1     = (const float*)d_in[13];
    const float* aW2     = (const float*)d_in[14];
    const float* ab2     = (const float*)d_in[15];
    const float* pW1     = (const float*)d_in[16];
    const float* pb1     = (const float*)d_in[17];
    const float* pW2     = (const float*)d_in[18];
    const float* pb2     = (const float*)d_in[19];
    const float* eW1     = (const float*)d_in[20];
    const float* eb1     = (const float*)d_in[21];
    const float* eW2     = (const float*)d_in[22];
    const float* eb2     = (const float*)d_in[23];
    const int*  nbrs     = (const int*)d_in[24];

    float* out_vi = (float*)d_out;             // [B,A,NCB] fp32
    float* outV   = (float*)d_out + BA*NCB;    // [B,A,N,NCB,3] fp32

    k_wt<<<56, 256, 0, stream>>>(fW1, fW2, f2W, pW1, pW2, eW1, eW2);
    k_yi<<<BA, NF, 0, stream>>>(xi, in2f_W);

    k_main<<<BA, 256, 0, stream>>>(r_ij, cos_ij, f_ij, nmask, nbrs,
                                   fb1, fb2, f2b,
                                   aW1, ab1, aW2, ab2,
                                   pb1, pb2, eb1, eb2,
                                   out_vi);

    k_V<<<BA, 256, 0, stream>>>(cos_ij, nbrs, outV);
}